// Round 4
// baseline (37762.970 us; speedup 1.0000x reference)
//
#include <hip/hip_runtime.h>

// Problem constants
#define Bn 4
#define Ln 256
#define Dn 256
#define Wn 8
#define NB 256           // persistent grid: one block per CU
#define BLD (Bn*Ln*Dn)   // 262144
#define BDD (Bn*Dn*Dn)   // 262144

// -------------------------------------------------------------------------
// kphi (elementwise poly) + gamma (GEMV + sigmoid)
// -------------------------------------------------------------------------
__global__ __launch_bounds__(256) void kphi_gamma_kernel(
    const float* __restrict__ k_al, const float* __restrict__ x,
    const float* __restrict__ poly, const float* __restrict__ gW,
    const float* __restrict__ gb, float* __restrict__ kphi,
    float* __restrict__ gamma)
{
    int wg = blockIdx.x, tid = threadIdx.x;
    int wave = tid >> 6, lane = tid & 63;
    int n = wg * 4 + wave;                 // token index 0..1023
    float gacc = 0.f;
#pragma unroll
    for (int c = 0; c < 4; ++c) {
        int e = lane + 64 * c;
        float kv = k_al[n * Dn + e];
        kphi[n * Dn + e] = poly[e] * kv + poly[Dn + e] * kv * kv;
        gacc += x[n * Dn + e] * gW[e];
    }
#pragma unroll
    for (int off = 32; off; off >>= 1) gacc += __shfl_xor(gacc, off);
    if (lane == 0) gamma[n] = 1.f / (1.f + expf(-(gacc + gb[0])));
}

// -------------------------------------------------------------------------
// tiled GEMM  out[n,m] = act( sum_e In[n,e]*Wm[m,e] + bias[m] )
// ACT: 0 none, 1 sigmoid, 2 sigmoid*0.1
// -------------------------------------------------------------------------
template <int ACT>
__global__ __launch_bounds__(256) void gemm_act_kernel(
    const float* __restrict__ In, const float* __restrict__ Wm,
    const float* __restrict__ bias, float* __restrict__ Out)
{
    __shared__ float ldsX[32 * 64];
    __shared__ float ldsW[64 * 65];
    int n0 = blockIdx.x * 32;
    int m0 = blockIdx.y * 64;
    int tid = threadIdx.x;
    float acc[8] = {0, 0, 0, 0, 0, 0, 0, 0};
    for (int j0 = 0; j0 < 256; j0 += 64) {
#pragma unroll
        for (int q = 0; q < 2; ++q) {
            int fi = tid + 256 * q; int row = fi >> 4; int c4 = (fi & 15) << 2;
            *(float4*)&ldsX[row * 64 + c4] =
                *(const float4*)&In[(n0 + row) * 256 + j0 + c4];
        }
#pragma unroll
        for (int q = 0; q < 4; ++q) {
            int fi = tid + 256 * q; int row = fi >> 4; int c4 = (fi & 15) << 2;
            float4 vv = *(const float4*)&Wm[(m0 + row) * 256 + j0 + c4];
            ldsW[(c4 + 0) * 65 + row] = vv.x;
            ldsW[(c4 + 1) * 65 + row] = vv.y;
            ldsW[(c4 + 2) * 65 + row] = vv.z;
            ldsW[(c4 + 3) * 65 + row] = vv.w;
        }
        __syncthreads();
        int m = tid & 63, ng = tid >> 6;
        for (int j = 0; j < 64; ++j) {
            float wv = ldsW[j * 65 + m];
#pragma unroll
            for (int r = 0; r < 8; ++r) acc[r] += ldsX[(ng * 8 + r) * 64 + j] * wv;
        }
        __syncthreads();
    }
    int m = tid & 63, ng = tid >> 6;
    float bv = bias[m0 + m];
#pragma unroll
    for (int r = 0; r < 8; ++r) {
        float vv = acc[r] + bv;
        if (ACT == 1) vv = 1.f / (1.f + expf(-vv));
        if (ACT == 2) vv = 0.1f / (1.f + expf(-vv));
        Out[(n0 + ng * 8 + r) * 256 + m0 + m] = vv;
    }
}

// -------------------------------------------------------------------------
// prologue: init working M,S (in d_out), zero ys, norm slots, barrier flags
// -------------------------------------------------------------------------
__global__ __launch_bounds__(256) void prologue_kernel(
    const float* __restrict__ Mprev, const float* __restrict__ Sprev,
    float* __restrict__ M, float* __restrict__ S,
    float* __restrict__ ys, float* __restrict__ normbuf,
    unsigned* __restrict__ flags)
{
    int gidx = blockIdx.x * 256 + threadIdx.x;
    ((float4*)M)[gidx] = ((const float4*)Mprev)[gidx];
    ((float4*)S)[gidx] = ((const float4*)Sprev)[gidx];
    float4 z = {0.f, 0.f, 0.f, 0.f};
    ((float4*)ys)[gidx] = z;
    if (gidx < Ln * Bn) normbuf[gidx] = 0.f;
    if (gidx < NB * 32) flags[gidx] = 0u;   // 256 slots, 128B-padded
}

// -------------------------------------------------------------------------
// contention-free grid barrier: per-block epoch flag (128B-padded slot),
// release-store own flag, all-threads poll all flags (relaxed agent-scope
// LOADS only -- zero RMW). Monotonic epoch, no reset, no leader.
// -------------------------------------------------------------------------
__device__ __forceinline__ void grid_sync(unsigned* flags, unsigned k)
{
    __syncthreads();
    __threadfence();   // release: make this block's phase writes visible
    if (threadIdx.x == 0)
        __hip_atomic_store(&flags[(unsigned)blockIdx.x * 32], k,
                           __ATOMIC_RELAXED, __HIP_MEMORY_SCOPE_AGENT);
    unsigned v = __hip_atomic_load(&flags[(unsigned)threadIdx.x * 32],
                                   __ATOMIC_RELAXED, __HIP_MEMORY_SCOPE_AGENT);
    while (__syncthreads_count((int)(v >= k)) != NB) {
        v = __hip_atomic_load(&flags[(unsigned)threadIdx.x * 32],
                              __ATOMIC_RELAXED, __HIP_MEMORY_SCOPE_AGENT);
    }
    __threadfence();   // acquire: drop stale L1/L2 lines before reading peers' writes
    __syncthreads();
}

// -------------------------------------------------------------------------
// persistent scan kernel: 256 blocks x 256 threads, 3 phases + 3 barriers
// per step. Phase bodies identical to the verified per-step kernels.
// -------------------------------------------------------------------------
__global__ void __launch_bounds__(256, 1) scan_kernel(
    const float* __restrict__ kphi, const float* __restrict__ vv,
    const float* __restrict__ gamma, const float* __restrict__ alpha,
    const float* __restrict__ eta, const float* __restrict__ theta,
    float* __restrict__ M, float* __restrict__ S, float* __restrict__ T,
    float* __restrict__ ys, float* __restrict__ normbuf,
    unsigned* __restrict__ flags)
{
    __shared__ float smem[4352];          // 17.4 KB, aliased per phase
    const int wg = blockIdx.x, tid = threadIdx.x;
    const int b = wg >> 6, id = wg & 63;
    unsigned kbar = 0;

    for (int t = 0; t < Ln; ++t) {
        // ================= Phase A: err + S update + ||S||^2 ==============
        {
            float* ldsMT = smem;               // [64][33] transposed M chunk
            float* ldsK  = smem + 64 * 33;     // [8][64]
            float* ldsE  = ldsK + 8 * 64;      // [8][32]
            float* ldsKe = ldsE + 8 * 32;      // [8][32]
            int d0 = (id >> 3) * 32, e0 = (id & 7) * 32;
            int w = tid >> 5, dd = tid & 31;
            int tok = t - 7 + w;
            float acc = 0.f;
            const float* Mb = M + (b * Dn + d0) * Dn;

            for (int j0 = 0; j0 < Dn; j0 += 64) {
#pragma unroll
                for (int q = 0; q < 2; ++q) {
                    int fi = tid + 256 * q; int row = fi >> 4; int c4 = (fi & 15) << 2;
                    float4 mv = *(const float4*)&Mb[row * Dn + j0 + c4];
                    ldsMT[(c4 + 0) * 33 + row] = mv.x;
                    ldsMT[(c4 + 1) * 33 + row] = mv.y;
                    ldsMT[(c4 + 2) * 33 + row] = mv.z;
                    ldsMT[(c4 + 3) * 33 + row] = mv.w;
                }
                if (tid < 128) {
                    int ww = tid >> 4, c4 = (tid & 15) << 2;
                    int tk = t - 7 + ww;
                    float4 kv = {0.f, 0.f, 0.f, 0.f};
                    if (tk >= 0) kv = *(const float4*)&kphi[(b * Ln + tk) * Dn + j0 + c4];
                    *(float4*)&ldsK[ww * 64 + c4] = kv;
                }
                __syncthreads();
                for (int j = 0; j < 64; ++j)
                    acc += ldsK[w * 64 + j] * ldsMT[j * 33 + dd];
                __syncthreads();
            }

            const int cwin = (t + 1 < Wn) ? (t + 1) : Wn;
            float gsc = 0.f, ev = 0.f, ke = 0.f;
            if (tok >= 0) {
                ev = acc - vv[(b * Ln + tok) * Dn + d0 + dd];
                gsc = gamma[b * Ln + tok] / (float)cwin;
                ke = kphi[(b * Ln + tok) * Dn + e0 + dd];
            }
            ldsE[w * 32 + dd] = ev * gsc;
            ldsKe[w * 32 + dd] = ke;
            __syncthreads();

            int ee = tid & 31, g2 = tid >> 5;
            float sumsq = 0.f;
#pragma unroll
            for (int r = 0; r < 4; ++r) {
                int d2 = g2 + 8 * r;
                float a2 = 0.f;
#pragma unroll
                for (int w2 = 0; w2 < Wn; ++w2)
                    a2 += ldsE[w2 * 32 + d2] * ldsKe[w2 * 32 + ee];
                int d = d0 + d2, e = e0 + ee;
                float th = theta[(b * Ln + t) * Dn + d];
                float* sp = &S[(b * Dn + d) * Dn + e];
                float sn = th * (*sp) + a2;
                *sp = sn;
                sumsq += sn * sn;
            }
#pragma unroll
            for (int off = 32; off; off >>= 1) sumsq += __shfl_xor(sumsq, off);
            if ((tid & 63) == 0) atomicAdd(&normbuf[t * Bn + b], sumsq);
        }
        grid_sync(flags, ++kbar);

        // ================= Phase B: T = S S^T =============================
        {
            float* Ai = smem;                  // [32][68]
            float* Ak = smem + 32 * 68;        // [32][68]
            int i0 = (id >> 3) * 32, k0 = (id & 7) * 32;
            int g = tid >> 5, kk = tid & 31;
            float acc[4] = {0, 0, 0, 0};
            const float* Sb = S + b * Dn * Dn;
            for (int j0 = 0; j0 < Dn; j0 += 64) {
#pragma unroll
                for (int q = 0; q < 2; ++q) {
                    int fi = tid + 256 * q; int row = fi >> 4; int c4 = (fi & 15) << 2;
                    *(float4*)&Ai[row * 68 + c4] = *(const float4*)&Sb[(i0 + row) * Dn + j0 + c4];
                    *(float4*)&Ak[row * 68 + c4] = *(const float4*)&Sb[(k0 + row) * Dn + j0 + c4];
                }
                __syncthreads();
#pragma unroll 4
                for (int jq = 0; jq < 16; ++jq) {
                    float4 bv = *(float4*)&Ak[kk * 68 + 4 * jq];
#pragma unroll
                    for (int r = 0; r < 4; ++r) {
                        float4 av = *(float4*)&Ai[(g + 8 * r) * 68 + 4 * jq];
                        acc[r] += av.x * bv.x + av.y * bv.y + av.z * bv.z + av.w * bv.w;
                    }
                }
                __syncthreads();
            }
#pragma unroll
            for (int r = 0; r < 4; ++r)
                T[(b * Dn + i0 + g + 8 * r) * Dn + k0 + kk] = acc[r];
        }
        grid_sync(flags, ++kbar);

        // ====== Phase C: TS=T*S ; NS ; M = a M - e NS ; y = M kphi_t ======
        {
            float* Ti  = smem;                 // [32][68]
            float* SlT = smem + 32 * 68;       // [32][68] transposed
            int i0 = (id >> 3) * 32, l0 = (id & 7) * 32;
            int g = tid >> 5, ll = tid & 31;
            float acc[4] = {0, 0, 0, 0};
            const float* Tb = T + b * Dn * Dn;
            const float* Sb = S + b * Dn * Dn;
            for (int j0 = 0; j0 < Dn; j0 += 64) {
#pragma unroll
                for (int q = 0; q < 2; ++q) {
                    int fi = tid + 256 * q;
                    int row = fi >> 4; int c4 = (fi & 15) << 2;
                    *(float4*)&Ti[row * 68 + c4] = *(const float4*)&Tb[(i0 + row) * Dn + j0 + c4];
                    int row2 = fi >> 3; int c42 = (fi & 7) << 2;
                    float4 sv = *(const float4*)&Sb[(j0 + row2) * Dn + l0 + c42];
                    SlT[(c42 + 0) * 68 + row2] = sv.x;
                    SlT[(c42 + 1) * 68 + row2] = sv.y;
                    SlT[(c42 + 2) * 68 + row2] = sv.z;
                    SlT[(c42 + 3) * 68 + row2] = sv.w;
                }
                __syncthreads();
#pragma unroll 4
                for (int jq = 0; jq < 16; ++jq) {
                    float4 bv = *(float4*)&SlT[ll * 68 + 4 * jq];
#pragma unroll
                    for (int r = 0; r < 4; ++r) {
                        float4 av = *(float4*)&Ti[(g + 8 * r) * 68 + 4 * jq];
                        acc[r] += av.x * bv.x + av.y * bv.y + av.z * bv.z + av.w * bv.w;
                    }
                }
                __syncthreads();
            }
            float sq = normbuf[t * Bn + b];
            float nrm = sqrtf(sq) + 1e-7f;
            float inv_n = 1.f / nrm;
            float w1 = 1.5f * inv_n;
            float w3 = 0.5f * inv_n * inv_n * inv_n;
            int l = l0 + ll;
            float kv = kphi[(b * Ln + t) * Dn + l];
#pragma unroll
            for (int r = 0; r < 4; ++r) {
                int i = i0 + g + 8 * r;
                float s_il = Sb[i * Dn + l];
                float ns = w1 * s_il - w3 * acc[r];
                float a = alpha[(b * Ln + t) * Dn + i];
                float e = eta[(b * Ln + t) * Dn + i];
                float* mp = &M[(b * Dn + i) * Dn + l];
                float mn = a * (*mp) - e * ns;
                *mp = mn;
                float py = mn * kv;
#pragma unroll
                for (int off = 16; off; off >>= 1) py += __shfl_xor(py, off);
                if (ll == 0) atomicAdd(&ys[(b * Ln + t) * Dn + i], py);
            }
        }
        grid_sync(flags, ++kbar);
    }
}

// -------------------------------------------------------------------------
extern "C" void kernel_launch(void* const* d_in, const int* in_sizes, int n_in,
                              void* d_out, int out_size, void* d_ws, size_t ws_size,
                              hipStream_t stream)
{
    const float* x       = (const float*)d_in[0];
    const float* k_al    = (const float*)d_in[1];
    const float* v       = (const float*)d_in[2];
    const float* M_prev  = (const float*)d_in[3];
    const float* S_prev  = (const float*)d_in[4];
    const float* poly    = (const float*)d_in[5];
    const float* alpha_W = (const float*)d_in[6];
    const float* alpha_b = (const float*)d_in[7];
    const float* eta_W   = (const float*)d_in[8];
    const float* eta_b   = (const float*)d_in[9];
    const float* theta_W = (const float*)d_in[10];
    const float* theta_b = (const float*)d_in[11];
    const float* gamma_W = (const float*)d_in[12];
    const float* gamma_b = (const float*)d_in[13];
    const float* out_W   = (const float*)d_in[14];
    const float* out_b   = (const float*)d_in[15];

    float* ws = (float*)d_ws;
    float* kphi    = ws;                 // 262144
    float* alphaB  = kphi   + BLD;       // 262144
    float* etaB    = alphaB + BLD;       // 262144
    float* thetaB  = etaB   + BLD;       // 262144
    float* gammaB  = thetaB + BLD;       // 1024
    float* Tws     = gammaB + Bn * Ln;   // 262144
    float* ysws    = Tws    + BDD;       // 262144
    float* normbuf = ysws   + BLD;       // 1024
    unsigned* flags = (unsigned*)(normbuf + Ln * Bn);  // 256 slots x 128B

    float* out_y = (float*)d_out;        // [B,L,D]
    float* Mout  = out_y + BLD;          // [B,D,D] working M, final in-place
    float* Sout  = Mout + BDD;           // [B,D,D] working S, final in-place

    // precompute
    hipLaunchKernelGGL(kphi_gamma_kernel, dim3(256), dim3(256), 0, stream,
                       k_al, x, poly, gamma_W, gamma_b, kphi, gammaB);
    hipLaunchKernelGGL((gemm_act_kernel<1>), dim3(32, 4), dim3(256), 0, stream,
                       x, alpha_W, alpha_b, alphaB);
    hipLaunchKernelGGL((gemm_act_kernel<2>), dim3(32, 4), dim3(256), 0, stream,
                       x, eta_W, eta_b, etaB);
    hipLaunchKernelGGL((gemm_act_kernel<1>), dim3(32, 4), dim3(256), 0, stream,
                       x, theta_W, theta_b, thetaB);
    hipLaunchKernelGGL(prologue_kernel, dim3(256), dim3(256), 0, stream,
                       M_prev, S_prev, Mout, Sout, ysws, normbuf, flags);

    // persistent scan (flag-array grid barriers; 1 block per CU)
    hipLaunchKernelGGL(scan_kernel, dim3(NB), dim3(256), 0, stream,
                       kphi, v, gammaB, alphaB, etaB, thetaB,
                       Mout, Sout, Tws, ysws, normbuf, flags);

    // out projection
    hipLaunchKernelGGL((gemm_act_kernel<0>), dim3(32, 4), dim3(256), 0, stream,
                       ysws, out_W, out_b, out_y);
}

// Round 5
// 16237.604 us; speedup vs baseline: 2.3256x; 2.3256x over previous
//
#include <hip/hip_runtime.h>

// Problem constants
#define Bn 4
#define Ln 256
#define Dn 256
#define Wn 8
#define NB 256           // persistent grid: one block per CU
#define BLD (Bn*Ln*Dn)   // 262144
#define BDD (Bn*Dn*Dn)   // 262144

// -------------------------------------------------------------------------
// Coherent (cross-XCD) scalar access helpers: relaxed agent-scope atomics
// compile to global_load/store_dword with sc0 sc1 -> bypass the non-coherent
// per-XCD L2, no cache-maintenance (wbinv) ever needed.
// -------------------------------------------------------------------------
__device__ __forceinline__ float ldc(const float* p) {
    return __hip_atomic_load(p, __ATOMIC_RELAXED, __HIP_MEMORY_SCOPE_AGENT);
}
__device__ __forceinline__ void stc(float* p, float v) {
    __hip_atomic_store(p, v, __ATOMIC_RELAXED, __HIP_MEMORY_SCOPE_AGENT);
}

// -------------------------------------------------------------------------
// kphi (elementwise poly) + gamma (GEMV + sigmoid)
// -------------------------------------------------------------------------
__global__ __launch_bounds__(256) void kphi_gamma_kernel(
    const float* __restrict__ k_al, const float* __restrict__ x,
    const float* __restrict__ poly, const float* __restrict__ gW,
    const float* __restrict__ gb, float* __restrict__ kphi,
    float* __restrict__ gamma)
{
    int wg = blockIdx.x, tid = threadIdx.x;
    int wave = tid >> 6, lane = tid & 63;
    int n = wg * 4 + wave;                 // token index 0..1023
    float gacc = 0.f;
#pragma unroll
    for (int c = 0; c < 4; ++c) {
        int e = lane + 64 * c;
        float kv = k_al[n * Dn + e];
        kphi[n * Dn + e] = poly[e] * kv + poly[Dn + e] * kv * kv;
        gacc += x[n * Dn + e] * gW[e];
    }
#pragma unroll
    for (int off = 32; off; off >>= 1) gacc += __shfl_xor(gacc, off);
    if (lane == 0) gamma[n] = 1.f / (1.f + expf(-(gacc + gb[0])));
}

// -------------------------------------------------------------------------
// tiled GEMM  out[n,m] = act( sum_e In[n,e]*Wm[m,e] + bias[m] )
// ACT: 0 none, 1 sigmoid, 2 sigmoid*0.1
// -------------------------------------------------------------------------
template <int ACT>
__global__ __launch_bounds__(256) void gemm_act_kernel(
    const float* __restrict__ In, const float* __restrict__ Wm,
    const float* __restrict__ bias, float* __restrict__ Out)
{
    __shared__ float ldsX[32 * 64];
    __shared__ float ldsW[64 * 65];
    int n0 = blockIdx.x * 32;
    int m0 = blockIdx.y * 64;
    int tid = threadIdx.x;
    float acc[8] = {0, 0, 0, 0, 0, 0, 0, 0};
    for (int j0 = 0; j0 < 256; j0 += 64) {
#pragma unroll
        for (int q = 0; q < 2; ++q) {
            int fi = tid + 256 * q; int row = fi >> 4; int c4 = (fi & 15) << 2;
            *(float4*)&ldsX[row * 64 + c4] =
                *(const float4*)&In[(n0 + row) * 256 + j0 + c4];
        }
#pragma unroll
        for (int q = 0; q < 4; ++q) {
            int fi = tid + 256 * q; int row = fi >> 4; int c4 = (fi & 15) << 2;
            float4 vv = *(const float4*)&Wm[(m0 + row) * 256 + j0 + c4];
            ldsW[(c4 + 0) * 65 + row] = vv.x;
            ldsW[(c4 + 1) * 65 + row] = vv.y;
            ldsW[(c4 + 2) * 65 + row] = vv.z;
            ldsW[(c4 + 3) * 65 + row] = vv.w;
        }
        __syncthreads();
        int m = tid & 63, ng = tid >> 6;
        for (int j = 0; j < 64; ++j) {
            float wv = ldsW[j * 65 + m];
#pragma unroll
            for (int r = 0; r < 8; ++r) acc[r] += ldsX[(ng * 8 + r) * 64 + j] * wv;
        }
        __syncthreads();
    }
    int m = tid & 63, ng = tid >> 6;
    float bv = bias[m0 + m];
#pragma unroll
    for (int r = 0; r < 8; ++r) {
        float vv = acc[r] + bv;
        if (ACT == 1) vv = 1.f / (1.f + expf(-vv));
        if (ACT == 2) vv = 0.1f / (1.f + expf(-vv));
        Out[(n0 + ng * 8 + r) * 256 + m0 + m] = vv;
    }
}

// -------------------------------------------------------------------------
// prologue: init working M,S (in d_out), zero ys, norm slots, barrier flags
// -------------------------------------------------------------------------
__global__ __launch_bounds__(256) void prologue_kernel(
    const float* __restrict__ Mprev, const float* __restrict__ Sprev,
    float* __restrict__ M, float* __restrict__ S,
    float* __restrict__ ys, float* __restrict__ normbuf,
    unsigned* __restrict__ flags)
{
    int gidx = blockIdx.x * 256 + threadIdx.x;
    ((float4*)M)[gidx] = ((const float4*)Mprev)[gidx];
    ((float4*)S)[gidx] = ((const float4*)Sprev)[gidx];
    float4 z = {0.f, 0.f, 0.f, 0.f};
    ((float4*)ys)[gidx] = z;
    if (gidx < Ln * Bn) normbuf[gidx] = 0.f;
    if (gidx < NB * 32) flags[gidx] = 0u;   // 256 slots, 128B-padded
}

// -------------------------------------------------------------------------
// fence-free grid barrier: drain own stores (vmcnt), block-sync, then
// release own 128B-padded epoch flag; poll all 256 flags with relaxed
// agent-scope loads. NO __threadfence -> no L2 writeback-invalidate.
// -------------------------------------------------------------------------
__device__ __forceinline__ void grid_sync(unsigned* flags, unsigned k)
{
    asm volatile("s_waitcnt vmcnt(0) lgkmcnt(0)" ::: "memory");
    __syncthreads();
    if (threadIdx.x == 0)
        __hip_atomic_store(&flags[(unsigned)blockIdx.x * 32u], k,
                           __ATOMIC_RELAXED, __HIP_MEMORY_SCOPE_AGENT);
    unsigned v = __hip_atomic_load(&flags[(unsigned)threadIdx.x * 32u],
                                   __ATOMIC_RELAXED, __HIP_MEMORY_SCOPE_AGENT);
    while (__syncthreads_count((int)(v >= k)) != NB) {
        __builtin_amdgcn_s_sleep(1);
        v = __hip_atomic_load(&flags[(unsigned)threadIdx.x * 32u],
                              __ATOMIC_RELAXED, __HIP_MEMORY_SCOPE_AGENT);
    }
    asm volatile("" ::: "memory");
}

// -------------------------------------------------------------------------
// persistent scan kernel: 256 blocks x 256 threads, 3 phases + 3 barriers
// per step. All cross-block mutable data (M,S,T,normbuf) accessed ONLY via
// ldc/stc (sc1); read-only data (kphi,v,gates) via normal cached loads.
// -------------------------------------------------------------------------
__global__ void __launch_bounds__(256, 1) scan_kernel(
    const float* __restrict__ kphi, const float* __restrict__ vv,
    const float* __restrict__ gamma, const float* __restrict__ alpha,
    const float* __restrict__ eta, const float* __restrict__ theta,
    float* __restrict__ M, float* __restrict__ S, float* __restrict__ T,
    float* __restrict__ ys, float* __restrict__ normbuf,
    unsigned* __restrict__ flags)
{
    __shared__ float smem[4352];          // 17.4 KB, aliased per phase
    const int wg = blockIdx.x, tid = threadIdx.x;
    const int b = wg >> 6, id = wg & 63;
    unsigned kbar = 0;

    for (int t = 0; t < Ln; ++t) {
        // ================= Phase A: err + S update + ||S||^2 ==============
        {
            float* ldsMT = smem;                 // [64][33] transposed M chunk
            float* ldsK  = smem + 2112;          // [8][64]
            float* ldsE  = smem + 2112 + 512;    // [8][32]
            float* ldsKe = ldsE + 256;           // [8][32]
            int d0 = (id >> 3) * 32, e0 = (id & 7) * 32;
            int w = tid >> 5, dd = tid & 31;
            int tok = t - 7 + w;
            float acc = 0.f;
            const float* Mb = M + (b * Dn + d0) * Dn;

            for (int j0 = 0; j0 < Dn; j0 += 64) {
                float tm[8];
#pragma unroll
                for (int q = 0; q < 8; ++q) {
                    int idx = q * 256 + tid;
                    int row = idx >> 6, col = idx & 63;
                    tm[q] = ldc(&Mb[row * Dn + j0 + col]);
                }
#pragma unroll
                for (int q = 0; q < 8; ++q) {
                    int idx = q * 256 + tid;
                    int row = idx >> 6, col = idx & 63;
                    ldsMT[col * 33 + row] = tm[q];
                }
                if (tid < 128) {
                    int ww = tid >> 4, c4 = (tid & 15) << 2;
                    int tk = t - 7 + ww;
                    float4 kv = {0.f, 0.f, 0.f, 0.f};
                    if (tk >= 0) kv = *(const float4*)&kphi[(b * Ln + tk) * Dn + j0 + c4];
                    *(float4*)&ldsK[ww * 64 + c4] = kv;
                }
                __syncthreads();
                for (int j = 0; j < 64; ++j)
                    acc += ldsK[w * 64 + j] * ldsMT[j * 33 + dd];
                __syncthreads();
            }

            const int cwin = (t + 1 < Wn) ? (t + 1) : Wn;
            float gsc = 0.f, ev = 0.f, ke = 0.f;
            if (tok >= 0) {
                ev = acc - vv[(b * Ln + tok) * Dn + d0 + dd];
                gsc = gamma[b * Ln + tok] / (float)cwin;
                ke = kphi[(b * Ln + tok) * Dn + e0 + dd];
            }
            ldsE[w * 32 + dd] = ev * gsc;
            ldsKe[w * 32 + dd] = ke;
            __syncthreads();

            int ee = tid & 31, g2 = tid >> 5;
            float sumsq = 0.f;
#pragma unroll
            for (int r = 0; r < 4; ++r) {
                int d2 = g2 + 8 * r;
                float a2 = 0.f;
#pragma unroll
                for (int w2 = 0; w2 < Wn; ++w2)
                    a2 += ldsE[w2 * 32 + d2] * ldsKe[w2 * 32 + ee];
                int d = d0 + d2, e = e0 + ee;
                float th = theta[(b * Ln + t) * Dn + d];
                float* sp = &S[(b * Dn + d) * Dn + e];
                float sn = th * ldc(sp) + a2;
                stc(sp, sn);
                sumsq += sn * sn;
            }
#pragma unroll
            for (int off = 32; off; off >>= 1) sumsq += __shfl_xor(sumsq, off);
            if ((tid & 63) == 0) atomicAdd(&normbuf[t * Bn + b], sumsq);
        }
        grid_sync(flags, ++kbar);

        // ================= Phase B: T = S S^T =============================
        {
            float* Ai = smem;                  // [32][68]
            float* Ak = smem + 2176;           // [32][68]
            int i0 = (id >> 3) * 32, k0 = (id & 7) * 32;
            int g = tid >> 5, kk = tid & 31;
            float acc[4] = {0, 0, 0, 0};
            const float* Sb = S + b * Dn * Dn;
            for (int j0 = 0; j0 < Dn; j0 += 64) {
                float ta[8], tb[8];
#pragma unroll
                for (int q = 0; q < 8; ++q) {
                    int idx = q * 256 + tid;
                    int row = idx >> 6, col = idx & 63;
                    ta[q] = ldc(&Sb[(i0 + row) * Dn + j0 + col]);
                    tb[q] = ldc(&Sb[(k0 + row) * Dn + j0 + col]);
                }
#pragma unroll
                for (int q = 0; q < 8; ++q) {
                    int idx = q * 256 + tid;
                    int row = idx >> 6, col = idx & 63;
                    Ai[row * 68 + col] = ta[q];
                    Ak[row * 68 + col] = tb[q];
                }
                __syncthreads();
#pragma unroll 4
                for (int jq = 0; jq < 16; ++jq) {
                    float4 bv = *(float4*)&Ak[kk * 68 + 4 * jq];
#pragma unroll
                    for (int r = 0; r < 4; ++r) {
                        float4 av = *(float4*)&Ai[(g + 8 * r) * 68 + 4 * jq];
                        acc[r] += av.x * bv.x + av.y * bv.y + av.z * bv.z + av.w * bv.w;
                    }
                }
                __syncthreads();
            }
#pragma unroll
            for (int r = 0; r < 4; ++r)
                stc(&T[(b * Dn + i0 + g + 8 * r) * Dn + k0 + kk], acc[r]);
        }
        grid_sync(flags, ++kbar);

        // ====== Phase C: TS=T*S ; NS ; M = a M - e NS ; y = M kphi_t ======
        {
            float* Ti   = smem;                // [32][68] T row-panel chunk
            float* ldsS = smem + 2176;         // [64][33] S[j][l-block]
            int i0 = (id >> 3) * 32, l0 = (id & 7) * 32;
            int g = tid >> 5, ll = tid & 31;
            float acc[4] = {0, 0, 0, 0};
            const float* Tb = T + b * Dn * Dn;
            const float* Sb = S + b * Dn * Dn;
            for (int j0 = 0; j0 < Dn; j0 += 64) {
                float ta[8], ts[8];
#pragma unroll
                for (int q = 0; q < 8; ++q) {
                    int idx = q * 256 + tid;
                    int row = idx >> 6, col = idx & 63;
                    ta[q] = ldc(&Tb[(i0 + row) * Dn + j0 + col]);
                    int lc = idx & 31, jr = idx >> 5;
                    ts[q] = ldc(&Sb[(j0 + jr) * Dn + l0 + lc]);
                }
#pragma unroll
                for (int q = 0; q < 8; ++q) {
                    int idx = q * 256 + tid;
                    int row = idx >> 6, col = idx & 63;
                    Ti[row * 68 + col] = ta[q];
                    int lc = idx & 31, jr = idx >> 5;
                    ldsS[jr * 33 + lc] = ts[q];
                }
                __syncthreads();
#pragma unroll 4
                for (int jq = 0; jq < 16; ++jq) {
                    float s0 = ldsS[(4 * jq + 0) * 33 + ll];
                    float s1 = ldsS[(4 * jq + 1) * 33 + ll];
                    float s2 = ldsS[(4 * jq + 2) * 33 + ll];
                    float s3 = ldsS[(4 * jq + 3) * 33 + ll];
#pragma unroll
                    for (int r = 0; r < 4; ++r) {
                        float4 av = *(float4*)&Ti[(g + 8 * r) * 68 + 4 * jq];
                        acc[r] += av.x * s0 + av.y * s1 + av.z * s2 + av.w * s3;
                    }
                }
                __syncthreads();
            }
            float sq = ldc(&normbuf[t * Bn + b]);
            float nrm = sqrtf(sq) + 1e-7f;
            float inv_n = 1.f / nrm;
            float w1 = 1.5f * inv_n;
            float w3 = 0.5f * inv_n * inv_n * inv_n;
            int l = l0 + ll;
            float kv = kphi[(b * Ln + t) * Dn + l];
#pragma unroll
            for (int r = 0; r < 4; ++r) {
                int i = i0 + g + 8 * r;
                float s_il = ldc(&Sb[i * Dn + l]);
                float ns = w1 * s_il - w3 * acc[r];
                float a = alpha[(b * Ln + t) * Dn + i];
                float e = eta[(b * Ln + t) * Dn + i];
                float* mp = &M[(b * Dn + i) * Dn + l];
                float mn = a * ldc(mp) - e * ns;
                stc(mp, mn);
                float py = mn * kv;
#pragma unroll
                for (int off = 16; off; off >>= 1) py += __shfl_xor(py, off);
                if (ll == 0) atomicAdd(&ys[(b * Ln + t) * Dn + i], py);
            }
        }
        grid_sync(flags, ++kbar);
    }
}

// -------------------------------------------------------------------------
extern "C" void kernel_launch(void* const* d_in, const int* in_sizes, int n_in,
                              void* d_out, int out_size, void* d_ws, size_t ws_size,
                              hipStream_t stream)
{
    const float* x       = (const float*)d_in[0];
    const float* k_al    = (const float*)d_in[1];
    const float* v       = (const float*)d_in[2];
    const float* M_prev  = (const float*)d_in[3];
    const float* S_prev  = (const float*)d_in[4];
    const float* poly    = (const float*)d_in[5];
    const float* alpha_W = (const float*)d_in[6];
    const float* alpha_b = (const float*)d_in[7];
    const float* eta_W   = (const float*)d_in[8];
    const float* eta_b   = (const float*)d_in[9];
    const float* theta_W = (const float*)d_in[10];
    const float* theta_b = (const float*)d_in[11];
    const float* gamma_W = (const float*)d_in[12];
    const float* gamma_b = (const float*)d_in[13];
    const float* out_W   = (const float*)d_in[14];
    const float* out_b   = (const float*)d_in[15];

    float* ws = (float*)d_ws;
    float* kphi    = ws;                 // 262144
    float* alphaB  = kphi   + BLD;       // 262144
    float* etaB    = alphaB + BLD;       // 262144
    float* thetaB  = etaB   + BLD;       // 262144
    float* gammaB  = thetaB + BLD;       // 1024
    float* Tws     = gammaB + Bn * Ln;   // 262144
    float* ysws    = Tws    + BDD;       // 262144
    float* normbuf = ysws   + BLD;       // 1024
    unsigned* flags = (unsigned*)(normbuf + Ln * Bn);  // 256 slots x 128B

    float* out_y = (float*)d_out;        // [B,L,D]
    float* Mout  = out_y + BLD;          // [B,D,D] working M, final in-place
    float* Sout  = Mout + BDD;           // [B,D,D] working S, final in-place

    // precompute
    hipLaunchKernelGGL(kphi_gamma_kernel, dim3(256), dim3(256), 0, stream,
                       k_al, x, poly, gamma_W, gamma_b, kphi, gammaB);
    hipLaunchKernelGGL((gemm_act_kernel<1>), dim3(32, 4), dim3(256), 0, stream,
                       x, alpha_W, alpha_b, alphaB);
    hipLaunchKernelGGL((gemm_act_kernel<2>), dim3(32, 4), dim3(256), 0, stream,
                       x, eta_W, eta_b, etaB);
    hipLaunchKernelGGL((gemm_act_kernel<1>), dim3(32, 4), dim3(256), 0, stream,
                       x, theta_W, theta_b, thetaB);
    hipLaunchKernelGGL(prologue_kernel, dim3(256), dim3(256), 0, stream,
                       M_prev, S_prev, Mout, Sout, ysws, normbuf, flags);

    // persistent scan (fence-free flag barriers; 1 block per CU)
    hipLaunchKernelGGL(scan_kernel, dim3(NB), dim3(256), 0, stream,
                       kphi, v, gammaB, alphaB, etaB, thetaB,
                       Mout, Sout, Tws, ysws, normbuf, flags);

    // out projection
    hipLaunchKernelGGL((gemm_act_kernel<0>), dim3(32, 4), dim3(256), 0, stream,
                       ysws, out_W, out_b, out_y);
}

// Round 6
// 5977.718 us; speedup vs baseline: 6.3173x; 2.7164x over previous
//
#include <hip/hip_runtime.h>

// Problem constants
#define Bn 4
#define Ln 256
#define Dn 256
#define Wn 8
#define NBLK 64          // persistent grid: 64 blocks (1 per CU, trivially co-resident)
#define BLD (Bn*Ln*Dn)   // 262144
#define BDD (Bn*Dn*Dn)   // 262144

typedef float  floatx4 __attribute__((ext_vector_type(4)));
typedef short  short8  __attribute__((ext_vector_type(8)));

// -------------------------------------------------------------------------
// Coherent (cross-XCD) access helpers. sc0 sc1 bypass L1/L2 -> MALL, so no
// cache-maintenance is ever needed. Batched asm loads keep 4-8 loads in
// flight per waitcnt (the round-5 scalar ldc's were latency-serialized).
// -------------------------------------------------------------------------
__device__ __forceinline__ float ldc(const float* p) {
    return __hip_atomic_load(p, __ATOMIC_RELAXED, __HIP_MEMORY_SCOPE_AGENT);
}
__device__ __forceinline__ void stc(float* p, float v) {
    __hip_atomic_store(p, v, __ATOMIC_RELAXED, __HIP_MEMORY_SCOPE_AGENT);
}
__device__ __forceinline__ void stc4(float* p, floatx4 v) {
    asm volatile("global_store_dwordx4 %0, %1, off sc0 sc1" :: "v"(p), "v"(v) : "memory");
}
__device__ __forceinline__ void ldc4x4(floatx4& a0, floatx4& a1, floatx4& a2, floatx4& a3,
    const float* p0, const float* p1, const float* p2, const float* p3)
{
    asm volatile(
        "global_load_dwordx4 %0, %4, off sc0 sc1\n\t"
        "global_load_dwordx4 %1, %5, off sc0 sc1\n\t"
        "global_load_dwordx4 %2, %6, off sc0 sc1\n\t"
        "global_load_dwordx4 %3, %7, off sc0 sc1\n\t"
        "s_waitcnt vmcnt(0)"
        : "=&v"(a0), "=&v"(a1), "=&v"(a2), "=&v"(a3)
        : "v"(p0), "v"(p1), "v"(p2), "v"(p3)
        : "memory");
}
__device__ __forceinline__ void ldc4x8(
    floatx4& a0, floatx4& a1, floatx4& a2, floatx4& a3,
    floatx4& b0, floatx4& b1, floatx4& b2, floatx4& b3,
    const float* p0, const float* p1, const float* p2, const float* p3,
    const float* q0, const float* q1, const float* q2, const float* q3)
{
    asm volatile(
        "global_load_dwordx4 %0, %8, off sc0 sc1\n\t"
        "global_load_dwordx4 %1, %9, off sc0 sc1\n\t"
        "global_load_dwordx4 %2, %10, off sc0 sc1\n\t"
        "global_load_dwordx4 %3, %11, off sc0 sc1\n\t"
        "global_load_dwordx4 %4, %12, off sc0 sc1\n\t"
        "global_load_dwordx4 %5, %13, off sc0 sc1\n\t"
        "global_load_dwordx4 %6, %14, off sc0 sc1\n\t"
        "global_load_dwordx4 %7, %15, off sc0 sc1\n\t"
        "s_waitcnt vmcnt(0)"
        : "=&v"(a0), "=&v"(a1), "=&v"(a2), "=&v"(a3),
          "=&v"(b0), "=&v"(b1), "=&v"(b2), "=&v"(b3)
        : "v"(p0), "v"(p1), "v"(p2), "v"(p3),
          "v"(q0), "v"(q1), "v"(q2), "v"(q3)
        : "memory");
}
__device__ __forceinline__ void ldc1x8(
    float& d0, float& d1, float& d2, float& d3,
    float& d4, float& d5, float& d6, float& d7,
    const float* p0, const float* p1, const float* p2, const float* p3,
    const float* p4, const float* p5, const float* p6, const float* p7)
{
    asm volatile(
        "global_load_dword %0, %8, off sc0 sc1\n\t"
        "global_load_dword %1, %9, off sc0 sc1\n\t"
        "global_load_dword %2, %10, off sc0 sc1\n\t"
        "global_load_dword %3, %11, off sc0 sc1\n\t"
        "global_load_dword %4, %12, off sc0 sc1\n\t"
        "global_load_dword %5, %13, off sc0 sc1\n\t"
        "global_load_dword %6, %14, off sc0 sc1\n\t"
        "global_load_dword %7, %15, off sc0 sc1\n\t"
        "s_waitcnt vmcnt(0)"
        : "=&v"(d0), "=&v"(d1), "=&v"(d2), "=&v"(d3),
          "=&v"(d4), "=&v"(d5), "=&v"(d6), "=&v"(d7)
        : "v"(p0), "v"(p1), "v"(p2), "v"(p3),
          "v"(p4), "v"(p5), "v"(p6), "v"(p7)
        : "memory");
}

// bf16 pack (RNE)
__device__ __forceinline__ unsigned f2bf(float x) {
    unsigned u = __float_as_uint(x);
    return (u + 0x7FFFu + ((u >> 16) & 1u)) >> 16;
}
__device__ __forceinline__ unsigned long long packbf4(floatx4 v) {
    unsigned lo = f2bf(v[0]) | (f2bf(v[1]) << 16);
    unsigned hi = f2bf(v[2]) | (f2bf(v[3]) << 16);
    return (unsigned long long)lo | ((unsigned long long)hi << 32);
}

// -------------------------------------------------------------------------
// fence-free grid barrier (64 blocks): drain own vmem, block-sync, release
// own 128B-padded epoch flag, single wave polls one flag per lane.
// -------------------------------------------------------------------------
__device__ __forceinline__ void grid_sync(unsigned* flags, unsigned k)
{
    asm volatile("s_waitcnt vmcnt(0) lgkmcnt(0)" ::: "memory");
    __syncthreads();
    if (threadIdx.x == 0)
        __hip_atomic_store(&flags[(unsigned)blockIdx.x * 32u], k,
                           __ATOMIC_RELAXED, __HIP_MEMORY_SCOPE_AGENT);
    if (threadIdx.x < NBLK) {
        while (__hip_atomic_load(&flags[(unsigned)threadIdx.x * 32u],
                                 __ATOMIC_RELAXED, __HIP_MEMORY_SCOPE_AGENT) < k)
            __builtin_amdgcn_s_sleep(1);
    }
    __syncthreads();
}

// -------------------------------------------------------------------------
// kphi (elementwise poly) + gamma (GEMV + sigmoid)   [verified round 2]
// -------------------------------------------------------------------------
__global__ __launch_bounds__(256) void kphi_gamma_kernel(
    const float* __restrict__ k_al, const float* __restrict__ x,
    const float* __restrict__ poly, const float* __restrict__ gW,
    const float* __restrict__ gb, float* __restrict__ kphi,
    float* __restrict__ gamma)
{
    int wg = blockIdx.x, tid = threadIdx.x;
    int wave = tid >> 6, lane = tid & 63;
    int n = wg * 4 + wave;
    float gacc = 0.f;
#pragma unroll
    for (int c = 0; c < 4; ++c) {
        int e = lane + 64 * c;
        float kv = k_al[n * Dn + e];
        kphi[n * Dn + e] = poly[e] * kv + poly[Dn + e] * kv * kv;
        gacc += x[n * Dn + e] * gW[e];
    }
#pragma unroll
    for (int off = 32; off; off >>= 1) gacc += __shfl_xor(gacc, off);
    if (lane == 0) gamma[n] = 1.f / (1.f + expf(-(gacc + gb[0])));
}

// -------------------------------------------------------------------------
// tiled GEMM out[n,m] = act(In · Wm^T + b)   [verified round 2]
// -------------------------------------------------------------------------
template <int ACT>
__global__ __launch_bounds__(256) void gemm_act_kernel(
    const float* __restrict__ In, const float* __restrict__ Wm,
    const float* __restrict__ bias, float* __restrict__ Out)
{
    __shared__ float ldsX[32 * 64];
    __shared__ float ldsW[64 * 65];
    int n0 = blockIdx.x * 32;
    int m0 = blockIdx.y * 64;
    int tid = threadIdx.x;
    float acc[8] = {0, 0, 0, 0, 0, 0, 0, 0};
    for (int j0 = 0; j0 < 256; j0 += 64) {
#pragma unroll
        for (int q = 0; q < 2; ++q) {
            int fi = tid + 256 * q; int row = fi >> 4; int c4 = (fi & 15) << 2;
            *(float4*)&ldsX[row * 64 + c4] =
                *(const float4*)&In[(n0 + row) * 256 + j0 + c4];
        }
#pragma unroll
        for (int q = 0; q < 4; ++q) {
            int fi = tid + 256 * q; int row = fi >> 4; int c4 = (fi & 15) << 2;
            float4 vv = *(const float4*)&Wm[(m0 + row) * 256 + j0 + c4];
            ldsW[(c4 + 0) * 65 + row] = vv.x;
            ldsW[(c4 + 1) * 65 + row] = vv.y;
            ldsW[(c4 + 2) * 65 + row] = vv.z;
            ldsW[(c4 + 3) * 65 + row] = vv.w;
        }
        __syncthreads();
        int m = tid & 63, ng = tid >> 6;
        for (int j = 0; j < 64; ++j) {
            float wv = ldsW[j * 65 + m];
#pragma unroll
            for (int r = 0; r < 8; ++r) acc[r] += ldsX[(ng * 8 + r) * 64 + j] * wv;
        }
        __syncthreads();
    }
    int m = tid & 63, ng = tid >> 6;
    float bv = bias[m0 + m];
#pragma unroll
    for (int r = 0; r < 8; ++r) {
        float vv = acc[r] + bv;
        if (ACT == 1) vv = 1.f / (1.f + expf(-vv));
        if (ACT == 2) vv = 0.1f / (1.f + expf(-vv));
        Out[(n0 + ng * 8 + r) * 256 + m0 + m] = vv;
    }
}

// -------------------------------------------------------------------------
// prologue: init M,S (in d_out), S^T copy, zero ys/normbuf/flags
// -------------------------------------------------------------------------
__global__ __launch_bounds__(256) void prologue_kernel(
    const float* __restrict__ Mprev, const float* __restrict__ Sprev,
    float* __restrict__ M, float* __restrict__ S, float* __restrict__ ST,
    float* __restrict__ ys, float* __restrict__ normbuf,
    unsigned* __restrict__ flags)
{
    int gidx = blockIdx.x * 256 + threadIdx.x;   // 0..65535
    ((float4*)M)[gidx] = ((const float4*)Mprev)[gidx];
    ((float4*)S)[gidx] = ((const float4*)Sprev)[gidx];
    float4 z = {0.f, 0.f, 0.f, 0.f};
    ((float4*)ys)[gidx] = z;
    {   // ST[b][l][k] = S_prev[b][k][l]
        int o = gidx * 4;
        int bb = o >> 16, rm = o & 65535, l = rm >> 8, k = rm & 255;
        float4 stv;
        stv.x = Sprev[bb * 65536 + (k + 0) * 256 + l];
        stv.y = Sprev[bb * 65536 + (k + 1) * 256 + l];
        stv.z = Sprev[bb * 65536 + (k + 2) * 256 + l];
        stv.w = Sprev[bb * 65536 + (k + 3) * 256 + l];
        ((float4*)ST)[gidx] = stv;
    }
    if (gidx < Ln * Bn) normbuf[gidx] = 0.f;
    if (gidx < NBLK * 32) flags[gidx] = 0u;
}

// -------------------------------------------------------------------------
// Persistent scan. 64 blocks x 256 threads. Per step:
//   Phase A (strip blocks, b x 16-row strip): err = M k_w, q = S_old k_w,
//     S_new = theta*S_old + sum_w u_w k_w^T (u = gamma*err/c), ||S||^2,
//     write S row-major + S^T, u/a vectors, k-gram K.
//   barrier
//   Phase C (b x 64x64 tile): T_new panel = thth*T_old + rank16 (fp32,
//     double-buffered), TS via bf16 MFMA 16x16x32, NS, M update, y.
//   barrier
// T invariant: T = S S^T maintained incrementally (theta scales outer
// indices of S S^T, so T_new = th th^T . T_old + U C^T + C U^T exactly).
// -------------------------------------------------------------------------
__global__ void __launch_bounds__(256, 1) scan_kernel(
    const float* __restrict__ kphi, const float* __restrict__ vin,
    const float* __restrict__ gammaB, const float* __restrict__ alphaB,
    const float* __restrict__ etaB, const float* __restrict__ thetaB,
    float* __restrict__ Mg, float* __restrict__ Sg, float* __restrict__ STg,
    float* __restrict__ T0g, float* __restrict__ T1g,
    float* __restrict__ u_buf, float* __restrict__ a_buf,
    float* __restrict__ K_buf, float* __restrict__ normbuf,
    float* __restrict__ ysg, unsigned* __restrict__ flags)
{
    __shared__ float smem[11072];       // 44.3 KB, aliased per phase
    const int wg = blockIdx.x, tid = threadIdx.x;
    const int b = wg >> 4;
    const int rem = wg & 15;
    const int i0 = (rem >> 2) * 64, l0 = (rem & 3) * 64;   // C-phase tile
    const int d0 = rem << 4;                               // A-phase strip
    const int wid = tid >> 6, lane = tid & 63;
    const int rb = (tid >> 4) << 2;     // 4-row group base (0..60)
    const int kb = (tid & 15) << 2;     // 4-col group base (0..60)
    char* TtB  = (char*)(smem + 6464);  // bf16 [64][72]
    char* StlB = (char*)(smem + 8768);  // bf16 [64][72]
    unsigned kbar = 0;

    // ============== init: T0 = S_prev S_prev^T (bf16 MFMA) ==============
    {
        floatx4 acc[4];
#pragma unroll
        for (int lt = 0; lt < 4; ++lt) acc[lt] = (floatx4){0.f, 0.f, 0.f, 0.f};
        const float* Sb = Sg + (size_t)b * Dn * Dn;
        for (int kc = 0; kc < 256; kc += 64) {
            floatx4 t0, t1, t2, t3, s0, s1, s2, s3;
            ldc4x8(t0, t1, t2, t3, s0, s1, s2, s3,
                   &Sb[(i0 + rb + 0) * Dn + kc + kb], &Sb[(i0 + rb + 1) * Dn + kc + kb],
                   &Sb[(i0 + rb + 2) * Dn + kc + kb], &Sb[(i0 + rb + 3) * Dn + kc + kb],
                   &Sb[(l0 + rb + 0) * Dn + kc + kb], &Sb[(l0 + rb + 1) * Dn + kc + kb],
                   &Sb[(l0 + rb + 2) * Dn + kc + kb], &Sb[(l0 + rb + 3) * Dn + kc + kb]);
            *(unsigned long long*)(TtB + (rb + 0) * 144 + kb * 2) = packbf4(t0);
            *(unsigned long long*)(TtB + (rb + 1) * 144 + kb * 2) = packbf4(t1);
            *(unsigned long long*)(TtB + (rb + 2) * 144 + kb * 2) = packbf4(t2);
            *(unsigned long long*)(TtB + (rb + 3) * 144 + kb * 2) = packbf4(t3);
            *(unsigned long long*)(StlB + (rb + 0) * 144 + kb * 2) = packbf4(s0);
            *(unsigned long long*)(StlB + (rb + 1) * 144 + kb * 2) = packbf4(s1);
            *(unsigned long long*)(StlB + (rb + 2) * 144 + kb * 2) = packbf4(s2);
            *(unsigned long long*)(StlB + (rb + 3) * 144 + kb * 2) = packbf4(s3);
            __syncthreads();
            const int arow = wid * 16 + (lane & 15);
#pragma unroll
            for (int ks = 0; ks < 2; ++ks) {
                const int kloc = ks * 32 + ((lane >> 4) << 3);
                short8 af = *(const short8*)(TtB + arow * 144 + kloc * 2);
#pragma unroll
                for (int lt = 0; lt < 4; ++lt) {
                    short8 bf = *(const short8*)(StlB + (lt * 16 + (lane & 15)) * 144 + kloc * 2);
                    acc[lt] = __builtin_amdgcn_mfma_f32_16x16x32_bf16(af, bf, acc[lt], 0, 0, 0);
                }
            }
            __syncthreads();
        }
        const int ibr = i0 + wid * 16 + ((lane >> 4) << 2);
        const int lc = lane & 15;
#pragma unroll
        for (int lt = 0; lt < 4; ++lt)
#pragma unroll
            for (int g = 0; g < 4; ++g)
                stc(&T0g[((size_t)b * Dn + ibr + g) * Dn + l0 + lt * 16 + lc], acc[lt][g]);
    }
    grid_sync(flags, ++kbar);

    for (int t = 0; t < Ln; ++t) {
        const int cwin = (t + 1 < Wn) ? (t + 1) : Wn;
        const float invc = 1.f / (float)cwin;

        // ========================= Phase A ==========================
        {
            float* kW  = smem;            // [8][260]
            float* Mst = smem + 2080;     // [16][260]  (aliased to Snew later)
            float* Sst = smem + 6240;     // [16][260]
            float* us  = smem + 10400;    // [8][16]
            float* as_ = smem + 10528;    // [8][16]
            float* ths = smem + 10656;    // [16]
            // ---- stage kphi window + theta + M/S strips
#pragma unroll
            for (int q = 0; q < 2; ++q) {
                int w = q * 4 + (tid >> 6);
                int c4 = (tid & 63) << 2;
                int tk = t - 7 + w;
                floatx4 kv = {0.f, 0.f, 0.f, 0.f};
                if (tk >= 0) kv = *(const floatx4*)&kphi[(b * Ln + tk) * Dn + c4];
                *(floatx4*)&kW[w * 260 + c4] = kv;
            }
            if (tid < 16) ths[tid] = thetaB[(b * Ln + t) * Dn + d0 + tid];
            {
                const float* mb = &Mg[((size_t)b * Dn + d0) * Dn];
                const float* sb = &Sg[((size_t)b * Dn + d0) * Dn];
                int ra = tid >> 6, c4 = (tid & 63) << 2;
                floatx4 m0, m1, m2, m3, s0, s1, s2, s3;
                ldc4x8(m0, m1, m2, m3, s0, s1, s2, s3,
                       &mb[(ra + 0) * Dn + c4], &mb[(ra + 4) * Dn + c4],
                       &mb[(ra + 8) * Dn + c4], &mb[(ra + 12) * Dn + c4],
                       &sb[(ra + 0) * Dn + c4], &sb[(ra + 4) * Dn + c4],
                       &sb[(ra + 8) * Dn + c4], &sb[(ra + 12) * Dn + c4]);
                *(floatx4*)&Mst[(ra + 0) * 260 + c4] = m0;
                *(floatx4*)&Mst[(ra + 4) * 260 + c4] = m1;
                *(floatx4*)&Mst[(ra + 8) * 260 + c4] = m2;
                *(floatx4*)&Mst[(ra + 12) * 260 + c4] = m3;
                *(floatx4*)&Sst[(ra + 0) * 260 + c4] = s0;
                *(floatx4*)&Sst[(ra + 4) * 260 + c4] = s1;
                *(floatx4*)&Sst[(ra + 8) * 260 + c4] = s2;
                *(floatx4*)&Sst[(ra + 12) * 260 + c4] = s3;
            }
            __syncthreads();
            // ---- dots: err_w = M_row . k_w ; q_w = S_row . k_w
            {
                const int w = tid >> 5, r = (tid >> 1) & 15, eh = tid & 1;
                const int eb = eh * 128;
                float em = 0.f, eq = 0.f;
                for (int j = 0; j < 128; j += 4) {
                    floatx4 kv = *(const floatx4*)&kW[w * 260 + eb + j];
                    floatx4 mv = *(const floatx4*)&Mst[r * 260 + eb + j];
                    floatx4 sv = *(const floatx4*)&Sst[r * 260 + eb + j];
                    em += kv[0] * mv[0] + kv[1] * mv[1] + kv[2] * mv[2] + kv[3] * mv[3];
                    eq += kv[0] * sv[0] + kv[1] * sv[1] + kv[2] * sv[2] + kv[3] * sv[3];
                }
                em += __shfl_xor(em, 1);
                eq += __shfl_xor(eq, 1);
                if (eh == 0) {
                    int tok = t - 7 + w;
                    float uu = 0.f;
                    if (tok >= 0) {
                        float ev = em - vin[(b * Ln + tok) * Dn + d0 + r];
                        uu = gammaB[b * Ln + tok] * invc * ev;
                    }
                    float aa = ths[r] * eq;   // eq==0 when tok<0 (kW zeroed)
                    us[w * 16 + r] = uu;
                    as_[w * 16 + r] = aa;
                    stc(&u_buf[(b * 8 + w) * Dn + d0 + r], uu);
                    stc(&a_buf[(b * 8 + w) * Dn + d0 + r], aa);
                }
            }
            // ---- k-gram (one strip-block per batch)
            if (rem == 0 && tid < 64) {
                int wa = tid >> 3, wb2 = tid & 7;
                float g = 0.f;
                for (int j = 0; j < 256; j += 4) {
                    floatx4 x1 = *(const floatx4*)&kW[wa * 260 + j];
                    floatx4 x2 = *(const floatx4*)&kW[wb2 * 260 + j];
                    g += x1[0] * x2[0] + x1[1] * x2[1] + x1[2] * x2[2] + x1[3] * x2[3];
                }
                stc(&K_buf[b * 64 + tid], g);
            }
            __syncthreads();
            // ---- S update (into Snew = Mst alias) + norm
            float* Snew = Mst;
            {
                int r = tid >> 4, m = tid & 15;
                float th = ths[r];
                float uu[8];
#pragma unroll
                for (int w = 0; w < 8; ++w) uu[w] = us[w * 16 + r];
                float sumsq = 0.f;
                for (int c = 0; c < 16; ++c) {
                    int e = m + 16 * c;
                    float sv = th * Sst[r * 260 + e];
#pragma unroll
                    for (int w = 0; w < 8; ++w) sv += uu[w] * kW[w * 260 + e];
                    Snew[r * 260 + e] = sv;
                    sumsq += sv * sv;
                }
#pragma unroll
                for (int off = 32; off; off >>= 1) sumsq += __shfl_xor(sumsq, off);
                if ((tid & 63) == 0) atomicAdd(&normbuf[t * Bn + b], sumsq);
            }
            __syncthreads();
            // ---- write S row-major + S^T
            {
                int r = tid >> 4, ec = (tid & 15) * 16;
                float* Sp = &Sg[((size_t)b * Dn + d0 + r) * Dn + ec];
#pragma unroll
                for (int c = 0; c < 4; ++c)
                    stc4(&Sp[c * 4], *(floatx4*)&Snew[r * 260 + ec + c * 4]);
            }
            {
                int lq = tid >> 4, r = tid & 15;
#pragma unroll
                for (int j = 0; j < 16; ++j) {
                    int l = lq * 16 + j;
                    stc(&STg[((size_t)b * Dn + l) * Dn + d0 + r], Snew[r * 260 + l]);
                }
            }
        }
        grid_sync(flags, ++kbar);

        // ========================= Phase C ==========================
        {
            float* uv  = smem;            // [8][256]
            float* av  = smem + 2048;     // [8][256]
            float* cv  = smem + 4096;     // [8][256]
            float* thv = smem + 6144;     // [256]
            float* Kl  = smem + 6400;     // [64]
            const float* Told = ((t & 1) ? T1g : T0g) + (size_t)b * Dn * Dn;
            float*       Tnew = ((t & 1) ? T0g : T1g) + (size_t)b * Dn * Dn;
            const float* STb = STg + (size_t)b * Dn * Dn;
            float nrmsq = ldc(&normbuf[t * Bn + b]);
            // ---- stage u,a vectors + theta + K
            {
                int fi0 = tid, fi1 = 256 + tid, fi2 = tid, fi3 = 256 + tid;
                floatx4 v0, v1, v2, v3;
                ldc4x4(v0, v1, v2, v3,
                       &u_buf[b * 2048 + fi0 * 4], &u_buf[b * 2048 + fi1 * 4],
                       &a_buf[b * 2048 + fi2 * 4], &a_buf[b * 2048 + fi3 * 4]);
                *(floatx4*)&uv[fi0 * 4] = v0;
                *(floatx4*)&uv[fi1 * 4] = v1;
                *(floatx4*)&av[fi2 * 4] = v2;
                *(floatx4*)&av[fi3 * 4] = v3;
                if (tid < 64) {
                    *(floatx4*)&thv[tid * 4] = *(const floatx4*)&thetaB[(b * Ln + t) * Dn + tid * 4];
                    Kl[tid] = ldc(&K_buf[b * 64 + tid]);
                }
            }
            __syncthreads();
            // ---- c = a + 0.5 K u
#pragma unroll
            for (int q = 0; q < 8; ++q) {
                int idx = q * 256 + tid;
                int w = idx >> 8, e = idx & 255;
                float s = av[idx];
#pragma unroll
                for (int w2 = 0; w2 < 8; ++w2) s += 0.5f * Kl[w * 8 + w2] * uv[w2 * 256 + e];
                cv[idx] = s;
            }
            __syncthreads();
            // ---- k-chunk loop: T panel update + MFMA TS
            floatx4 acc[4];
#pragma unroll
            for (int lt = 0; lt < 4; ++lt) acc[lt] = (floatx4){0.f, 0.f, 0.f, 0.f};
            for (int kc = 0; kc < 256; kc += 64) {
                floatx4 tv0, tv1, tv2, tv3, s0, s1, s2, s3;
                ldc4x8(tv0, tv1, tv2, tv3, s0, s1, s2, s3,
                       &Told[(i0 + rb + 0) * Dn + kc + kb], &Told[(i0 + rb + 1) * Dn + kc + kb],
                       &Told[(i0 + rb + 2) * Dn + kc + kb], &Told[(i0 + rb + 3) * Dn + kc + kb],
                       &STb[(l0 + rb + 0) * Dn + kc + kb], &STb[(l0 + rb + 1) * Dn + kc + kb],
                       &STb[(l0 + rb + 2) * Dn + kc + kb], &STb[(l0 + rb + 3) * Dn + kc + kb]);
                floatx4 tvv[4] = {tv0, tv1, tv2, tv3};
                floatx4 thk = *(floatx4*)&thv[kc + kb];
#pragma unroll
                for (int x = 0; x < 4; ++x) {
                    float thi = thv[i0 + rb + x];
                    tvv[x] = (thi * thk) * tvv[x];
                }
#pragma unroll
                for (int w = 0; w < 8; ++w) {
                    floatx4 ui = *(floatx4*)&uv[w * 256 + i0 + rb];
                    floatx4 ci = *(floatx4*)&cv[w * 256 + i0 + rb];
                    floatx4 uk = *(floatx4*)&uv[w * 256 + kc + kb];
                    floatx4 ck = *(floatx4*)&cv[w * 256 + kc + kb];
#pragma unroll
                    for (int x = 0; x < 4; ++x)
                        tvv[x] += ui[x] * ck + ci[x] * uk;
                }
                if (l0 == 0) {
#pragma unroll
                    for (int x = 0; x < 4; ++x)
                        stc4(&Tnew[(i0 + rb + x) * Dn + kc + kb], tvv[x]);
                }
                floatx4 svv_[4] = {s0, s1, s2, s3};
#pragma unroll
                for (int x = 0; x < 4; ++x) {
                    *(unsigned long long*)(TtB + (rb + x) * 144 + kb * 2) = packbf4(tvv[x]);
                    *(unsigned long long*)(StlB + (rb + x) * 144 + kb * 2) = packbf4(svv_[x]);
                }
                __syncthreads();
                const int arow = wid * 16 + (lane & 15);
#pragma unroll
                for (int ks = 0; ks < 2; ++ks) {
                    const int kloc = ks * 32 + ((lane >> 4) << 3);
                    short8 af = *(const short8*)(TtB + arow * 144 + kloc * 2);
#pragma unroll
                    for (int lt = 0; lt < 4; ++lt) {
                        short8 bf = *(const short8*)(StlB + (lt * 16 + (lane & 15)) * 144 + kloc * 2);
                        acc[lt] = __builtin_amdgcn_mfma_f32_16x16x32_bf16(af, bf, acc[lt], 0, 0, 0);
                    }
                }
                __syncthreads();
            }
            // ---- epilogue: NS, M update, y
            {
                float nrm = sqrtf(nrmsq) + 1e-7f;
                float inv_n = 1.f / nrm;
                float w1 = 1.5f * inv_n;
                float w3 = 0.5f * inv_n * inv_n * inv_n;
                const int ibr = i0 + wid * 16 + ((lane >> 4) << 2);
                const int lc = lane & 15;
                float* Mb = Mg + (size_t)b * Dn * Dn;
                const float* sp[16]; float* mp[16];
#pragma unroll
                for (int lt = 0; lt < 4; ++lt)
#pragma unroll
                    for (int g = 0; g < 4; ++g) {
                        int l = l0 + lt * 16 + lc;
                        sp[lt * 4 + g] = &STb[l * Dn + ibr + g];
                        mp[lt * 4 + g] = &Mb[(ibr + g) * Dn + l];
                    }
                float svv[16], mvv[16];
                ldc1x8(svv[0], svv[1], svv[2], svv[3], svv[4], svv[5], svv[6], svv[7],
                       sp[0], sp[1], sp[2], sp[3], sp[4], sp[5], sp[6], sp[7]);
                ldc1x8(svv[8], svv[9], svv[10], svv[11], svv[12], svv[13], svv[14], svv[15],
                       sp[8], sp[9], sp[10], sp[11], sp[12], sp[13], sp[14], sp[15]);
                ldc1x8(mvv[0], mvv[1], mvv[2], mvv[3], mvv[4], mvv[5], mvv[6], mvv[7],
                       mp[0], mp[1], mp[2], mp[3], mp[4], mp[5], mp[6], mp[7]);
                ldc1x8(mvv[8], mvv[9], mvv[10], mvv[11], mvv[12], mvv[13], mvv[14], mvv[15],
                       mp[8], mp[9], mp[10], mp[11], mp[12], mp[13], mp[14], mp[15]);
                float alv[4], etv[4];
#pragma unroll
                for (int g = 0; g < 4; ++g) {
                    alv[g] = alphaB[(b * Ln + t) * Dn + ibr + g];
                    etv[g] = etaB[(b * Ln + t) * Dn + ibr + g];
                }
                float kvr[4];
#pragma unroll
                for (int lt = 0; lt < 4; ++lt)
                    kvr[lt] = kphi[(b * Ln + t) * Dn + l0 + lt * 16 + lc];
                float py[4] = {0.f, 0.f, 0.f, 0.f};
#pragma unroll
                for (int lt = 0; lt < 4; ++lt)
#pragma unroll
                    for (int g = 0; g < 4; ++g) {
                        int idx = lt * 4 + g;
                        float ns = w1 * svv[idx] - w3 * acc[lt][g];
                        float mn = alv[g] * mvv[idx] - etv[g] * ns;
                        stc(mp[idx], mn);
                        py[g] += mn * kvr[lt];
                    }
#pragma unroll
                for (int g = 0; g < 4; ++g) {
                    float p = py[g];
                    p += __shfl_xor(p, 1); p += __shfl_xor(p, 2);
                    p += __shfl_xor(p, 4); p += __shfl_xor(p, 8);
                    if (lc == 0) atomicAdd(&ysg[(b * Ln + t) * Dn + ibr + g], p);
                }
            }
        }
        grid_sync(flags, ++kbar);
    }
}

// -------------------------------------------------------------------------
extern "C" void kernel_launch(void* const* d_in, const int* in_sizes, int n_in,
                              void* d_out, int out_size, void* d_ws, size_t ws_size,
                              hipStream_t stream)
{
    const float* x       = (const float*)d_in[0];
    const float* k_al    = (const float*)d_in[1];
    const float* v       = (const float*)d_in[2];
    const float* M_prev  = (const float*)d_in[3];
    const float* S_prev  = (const float*)d_in[4];
    const float* poly    = (const float*)d_in[5];
    const float* alpha_W = (const float*)d_in[6];
    const float* alpha_b = (const float*)d_in[7];
    const float* eta_W   = (const float*)d_in[8];
    const float* eta_b   = (const float*)d_in[9];
    const float* theta_W = (const float*)d_in[10];
    const float* theta_b = (const float*)d_in[11];
    const float* gamma_W = (const float*)d_in[12];
    const float* gamma_b = (const float*)d_in[13];
    const float* out_W   = (const float*)d_in[14];
    const float* out_b   = (const float*)d_in[15];

    float* ws = (float*)d_ws;
    float* kphi    = ws;                  // 262144
    float* alphaB  = kphi   + BLD;        // 262144
    float* etaB    = alphaB + BLD;        // 262144
    float* thetaB  = etaB   + BLD;        // 262144
    float* gammaB  = thetaB + BLD;        // 1024
    float* STws    = gammaB + Bn * Ln;    // 262144  (S^T)
    float* T0ws    = STws   + BDD;        // 262144  (T double-buffer)
    float* T1ws    = T0ws   + BDD;        // 262144
    float* ysws    = T1ws   + BDD;        // 262144
    float* u_bufp  = ysws   + BLD;        // 8192
    float* a_bufp  = u_bufp + Bn*Wn*Dn;   // 8192
    float* K_bufp  = a_bufp + Bn*Wn*Dn;   // 256
    float* normbuf = K_bufp + Bn*64;      // 1024
    unsigned* flags = (unsigned*)(normbuf + Ln * Bn);  // 64 x 32 u32

    float* out_y = (float*)d_out;         // [B,L,D]
    float* Mout  = out_y + BLD;           // [B,D,D] working M (final in place)
    float* Sout  = Mout + BDD;            // [B,D,D] working S (final in place)

    // precompute
    hipLaunchKernelGGL(kphi_gamma_kernel, dim3(256), dim3(256), 0, stream,
                       k_al, x, poly, gamma_W, gamma_b, kphi, gammaB);
    hipLaunchKernelGGL((gemm_act_kernel<1>), dim3(32, 4), dim3(256), 0, stream,
                       x, alpha_W, alpha_b, alphaB);
    hipLaunchKernelGGL((gemm_act_kernel<2>), dim3(32, 4), dim3(256), 0, stream,
                       x, eta_W, eta_b, etaB);
    hipLaunchKernelGGL((gemm_act_kernel<1>), dim3(32, 4), dim3(256), 0, stream,
                       x, theta_W, theta_b, thetaB);
    hipLaunchKernelGGL(prologue_kernel, dim3(256), dim3(256), 0, stream,
                       M_prev, S_prev, Mout, Sout, STws, ysws, normbuf, flags);

    // persistent scan
    hipLaunchKernelGGL(scan_kernel, dim3(NBLK), dim3(256), 0, stream,
                       kphi, v, gammaB, alphaB, etaB, thetaB,
                       Mout, Sout, STws, T0ws, T1ws,
                       u_bufp, a_bufp, K_bufp, normbuf, ysws, flags);

    // out projection
    hipLaunchKernelGGL((gemm_act_kernel<0>), dim3(32, 4), dim3(256), 0, stream,
                       ysws, out_W, out_b, out_y);
}